// Round 12
// baseline (47.992 us; speedup 1.0000x reference)
//
#include <hip/hip_runtime.h>

typedef unsigned long long u64;
typedef unsigned int u32;

#define B_  32
#define S_  1024
#define K_  16
#define NTK 256     // threads/block
#define QPB 32      // queries per block (NTK/8)

// key = double whose bit pattern is (d2_f32_bits << 32) | j.
// d2 >= 0 -> high word in [0, 0x7F7FFFFF] -> positive finite double,
// so IEEE fmin/fmax (v_min_f64/v_max_f64) order keys exactly as u64.
__device__ __forceinline__ double pack_key(float d2, int j) {
    return __longlong_as_double(((u64)__float_as_uint(d2) << 32) | (u32)j);
}

// ascending compare-exchange: 2 VALU instrs
__device__ __forceinline__ void ce(double& a, double& b) {
    const double lo = fmin(a, b);
    const double hi = fmax(a, b);
    a = lo; b = hi;
}

// Batcher odd-even mergesort of 8 keys, 19 CE, depth 6, ascending
__device__ __forceinline__ void sort8(double (&k)[8]) {
    ce(k[0], k[1]); ce(k[2], k[3]); ce(k[4], k[5]); ce(k[6], k[7]);
    ce(k[0], k[2]); ce(k[1], k[3]); ce(k[4], k[6]); ce(k[5], k[7]);
    ce(k[1], k[2]); ce(k[5], k[6]);
    ce(k[0], k[4]); ce(k[1], k[5]); ce(k[2], k[6]); ce(k[3], k[7]);
    ce(k[2], k[4]); ce(k[3], k[5]);
    ce(k[1], k[2]); ce(k[3], k[4]); ce(k[5], k[6]);
}

// clean a bitonic 16-sequence into ascending order (4 stages, 32 CE)
__device__ __forceinline__ void clean16(double (&k)[16]) {
#pragma unroll
    for (int str = 8; str > 0; str >>= 1) {
#pragma unroll
        for (int t = 0; t < 16; ++t) {
            const int p = t ^ str;
            if (p > t) ce(k[t], k[p]);
        }
    }
}

// Batcher odd-even merge of two sorted 2-lists: (p0,p1),(q0,q1) -> r0..r3, 3 CE
__device__ __forceinline__ void merge2(double p0, double p1, double q0, double q1,
                                       double& r0, double& r1, double& r2, double& r3) {
    ce(p0, q0);          // e0=p0, e1=q0
    ce(p1, q1);          // o0=p1, o1=q1
    r0 = p0; r3 = q1;
    ce(p1, q0);          // CE(o0, e1)
    r1 = p1; r2 = q0;
}

// Batcher odd-even merge of two sorted 4-lists -> r[0..7], 9 CE
__device__ __forceinline__ void merge4(double p0, double p1, double p2, double p3,
                                       double q0, double q1, double q2, double q3,
                                       double (&r)[8]) {
    double e0, e1, e2, e3, o0, o1, o2, o3;
    merge2(p0, p2, q0, q2, e0, e1, e2, e3);   // evens
    merge2(p1, p3, q1, q3, o0, o1, o2, o3);   // odds
    r[0] = e0; r[7] = o3;
    ce(o0, e1); r[1] = o0; r[2] = e1;
    ce(o1, e2); r[3] = o1; r[4] = e2;
    ce(o2, e3); r[5] = o2; r[6] = e3;
}

// Batcher odd-even merge of two sorted 8-lists -> c[0..15], 25 CE
__device__ __forceinline__ void merge8(const double (&a)[8], const double (&b)[8],
                                       double (&c)[16]) {
    double e[8], o[8];
    merge4(a[0], a[2], a[4], a[6], b[0], b[2], b[4], b[6], e);   // evens
    merge4(a[1], a[3], a[5], a[7], b[1], b[3], b[5], b[7], o);   // odds
    c[0] = e[0]; c[15] = o[7];
#pragma unroll
    for (int i = 0; i < 7; ++i) {           // combine: CE(o[i], e[i+1])
        double lo = o[i], hi = e[i + 1];
        ce(lo, hi);
        c[2 * i + 1] = lo; c[2 * i + 2] = hi;
    }
}

__global__ __launch_bounds__(NTK, 4)
void knn_fused(const float* __restrict__ pos, const float* __restrict__ x,
               const float* __restrict__ Wm, const float* __restrict__ bv,
               float* __restrict__ out) {
    __shared__ float4 spos[S_];             // 16 KB

    const int tid   = threadIdx.x;
    const int cloud = blockIdx.x >> 5;      // 32 blocks per cloud
    const int qbase = (blockIdx.x & 31) * QPB;
    const int base  = cloud * S_;

    for (int r = tid; r < S_; r += NTK) {
        const float* p = pos + (size_t)(base + r) * 3;
        spos[r] = make_float4(p[0], p[1], p[2], 0.0f);
    }
    __syncthreads();

    const int s  = tid & 7;                 // slice: j = s (mod 8)
    const int qi = qbase + (tid >> 3);      // query within cloud
    const float4 pi = spos[qi];
    const float pix = pi.x, piy = pi.y, piz = pi.z;

    double key[16];
#pragma unroll
    for (int t = 0; t < 16; ++t)
        key[t] = __longlong_as_double(0x7FEFFFFFFFFFFFFFULL);  // > any real key

    const float4* sp = &spos[s];            // lane slice pointer, stride 8
    float4 buf[8];                          // software-pipelined chunk loads
#pragma unroll
    for (int u = 0; u < 8; ++u) buf[u] = sp[8 * u];

    int jlow = s;                           // local j of buf[0]
    for (int c = 0; c < 8; ++c) {           // 8 iters x 16 candidates = 128
        double nk[8], mk[8];
        // batch A: candidates jlow + 8u
#pragma unroll
        for (int u = 0; u < 8; ++u) {
            // bit-exact numpy chain: no fma, (dx2+dy2)+dz2
            const float dx = __fsub_rn(pix, buf[u].x);
            const float dy = __fsub_rn(piy, buf[u].y);
            const float dz = __fsub_rn(piz, buf[u].z);
            const float d2 = __fadd_rn(
                __fadd_rn(__fmul_rn(dx, dx), __fmul_rn(dy, dy)),
                __fmul_rn(dz, dz));
            nk[u] = pack_key(d2, jlow + 8 * u);
        }
        sp += 64;                           // load batch B (hidden under sortA)
#pragma unroll
        for (int u = 0; u < 8; ++u) buf[u] = sp[8 * u];
        sort8(nk);

        // batch B: candidates jlow + 64 + 8u
#pragma unroll
        for (int u = 0; u < 8; ++u) {
            const float dx = __fsub_rn(pix, buf[u].x);
            const float dy = __fsub_rn(piy, buf[u].y);
            const float dz = __fsub_rn(piz, buf[u].z);
            const float d2 = __fadd_rn(
                __fadd_rn(__fmul_rn(dx, dx), __fmul_rn(dy, dy)),
                __fmul_rn(dz, dz));
            mk[u] = pack_key(d2, jlow + 64 + 8 * u);
        }
        sort8(mk);

        double m16[16];
        merge8(nk, mk, m16);                // sorted 16 new candidates (25 CE)

        if (c < 7) {                        // next batch A (hidden under clean)
            sp += 64;
#pragma unroll
            for (int u = 0; u < 8; ++u) buf[u] = sp[8 * u];
        }

        // keep 16 smallest of key ∪ m16: reversed pairwise min -> bitonic
#pragma unroll
        for (int t = 0; t < 16; ++t)
            key[t] = fmin(key[t], m16[15 - t]);
        clean16(key);

        jlow += 128;
    }

    // butterfly merge of the 8 slice lists; afterwards ALL 8 lanes of a
    // group hold the identical ascending top-16 of the query.
#pragma unroll
    for (int r = 1; r <= 4; r <<= 1) {
        double nk[16];
#pragma unroll
        for (int t = 0; t < 16; ++t)
            nk[t] = __shfl_xor(key[15 - t], r, 64);  // reversed partner list
#pragma unroll
        for (int t = 0; t < 16; ++t)
            key[t] = fmin(key[t], nk[t]);            // stride-16 half-cleaner
        clean16(key);
    }

    // ---- fused epilogue: each group of 8 lanes emits its query's 16 rows ----
    const float4* x4 = (const float4*)x;
    const float4* W4 = (const float4*)Wm;   // W[10][32]: row = 8 float4
    float4 wcol[10];
#pragma unroll
    for (int m = 0; m < 10; ++m) wcol[m] = W4[m * 8 + s];
    const float4 bb = ((const float4*)bv)[s];

    float4* orow = (float4*)out + (size_t)(base + qi) * (K_ * 16);
#pragma unroll
    for (int k = 0; k < 16; ++k) {
        const int jl = (int)(u32)__double_as_longlong(key[k]);   // local j
        // channels 4s..4s+3 of x_j (lane-coalesced 128B per group)
        const float4 xj = x4[(size_t)(base + jl) * 8 + s];
        // enc channels 32+4s..32+4s+3
        const float4 pj = spos[jl];                              // broadcast
        const float rx = pix - pj.x, ry = piy - pj.y, rz = piz - pj.z;
        const float dist = sqrtf(rx * rx + ry * ry + rz * rz + 1e-12f);
        const float f[10] = {pix, piy, piz, pj.x, pj.y, pj.z, rx, ry, rz, dist};
        float4 acc = bb;
#pragma unroll
        for (int m = 0; m < 10; ++m) {
            acc.x = fmaf(f[m], wcol[m].x, acc.x);
            acc.y = fmaf(f[m], wcol[m].y, acc.y);
            acc.z = fmaf(f[m], wcol[m].z, acc.z);
            acc.w = fmaf(f[m], wcol[m].w, acc.w);
        }
        acc.x = fmaxf(acc.x, 0.0f);
        acc.y = fmaxf(acc.y, 0.0f);
        acc.z = fmaxf(acc.z, 0.0f);
        acc.w = fmaxf(acc.w, 0.0f);
        orow[k * 16 + s]     = xj;
        orow[k * 16 + 8 + s] = acc;
    }
}

extern "C" void kernel_launch(void* const* d_in, const int* in_sizes, int n_in,
                              void* d_out, int out_size, void* d_ws, size_t ws_size,
                              hipStream_t stream) {
    const float* x   = (const float*)d_in[0];
    const float* pos = (const float*)d_in[1];
    // d_in[2] = batch (unused: equal-size contiguous clouds)
    const float* Wm  = (const float*)d_in[3];
    const float* bv  = (const float*)d_in[4];
    float* out = (float*)d_out;

    knn_fused<<<B_ * 32, NTK, 0, stream>>>(pos, x, Wm, bv, out);
}

// Round 13
// 47.366 us; speedup vs baseline: 1.0132x; 1.0132x over previous
//
#include <hip/hip_runtime.h>

typedef unsigned long long u64;
typedef unsigned int u32;

#define B_  32
#define S_  1024
#define K_  16
#define NTK 256     // threads/block
#define QPB 32      // queries per block (NTK/8)

// key = double whose bit pattern is (d2_f32_bits << 32) | j.
// d2 >= 0 -> high word in [0, 0x7F7FFFFF] -> positive finite double,
// so IEEE fmin/fmax (v_min_f64/v_max_f64) order keys exactly as u64.
__device__ __forceinline__ double pack_key(float d2, int j) {
    return __longlong_as_double(((u64)__float_as_uint(d2) << 32) | (u32)j);
}

// ascending compare-exchange: 2 VALU instrs
__device__ __forceinline__ void ce(double& a, double& b) {
    const double lo = fmin(a, b);
    const double hi = fmax(a, b);
    a = lo; b = hi;
}

// Batcher odd-even mergesort of 8 keys, 19 CE, depth 6, ascending
__device__ __forceinline__ void sort8(double (&k)[8]) {
    ce(k[0], k[1]); ce(k[2], k[3]); ce(k[4], k[5]); ce(k[6], k[7]);
    ce(k[0], k[2]); ce(k[1], k[3]); ce(k[4], k[6]); ce(k[5], k[7]);
    ce(k[1], k[2]); ce(k[5], k[6]);
    ce(k[0], k[4]); ce(k[1], k[5]); ce(k[2], k[6]); ce(k[3], k[7]);
    ce(k[2], k[4]); ce(k[3], k[5]);
    ce(k[1], k[2]); ce(k[3], k[4]); ce(k[5], k[6]);
}

// clean a bitonic 16-sequence into ascending order (4 stages, 32 CE)
__device__ __forceinline__ void clean16(double (&k)[16]) {
#pragma unroll
    for (int str = 8; str > 0; str >>= 1) {
#pragma unroll
        for (int t = 0; t < 16; ++t) {
            const int p = t ^ str;
            if (p > t) ce(k[t], k[p]);
        }
    }
}

__global__ __launch_bounds__(NTK, 4)
void knn_fused(const float* __restrict__ pos, const float* __restrict__ x,
               const float* __restrict__ Wm, const float* __restrict__ bv,
               float* __restrict__ out) {
    __shared__ float4 spos[S_];             // 16 KB

    const int tid   = threadIdx.x;
    const int cloud = blockIdx.x >> 5;      // 32 blocks per cloud
    const int qbase = (blockIdx.x & 31) * QPB;
    const int base  = cloud * S_;

    for (int r = tid; r < S_; r += NTK) {
        const float* p = pos + (size_t)(base + r) * 3;
        spos[r] = make_float4(p[0], p[1], p[2], 0.0f);
    }
    __syncthreads();

    const int s  = tid & 7;                 // slice: j = s (mod 8)
    const int qi = qbase + (tid >> 3);      // query within cloud
    const float4 pi = spos[qi];
    const float pix = pi.x, piy = pi.y, piz = pi.z;

    double key[16];
#pragma unroll
    for (int t = 0; t < 16; ++t)
        key[t] = __longlong_as_double(0x7FEFFFFFFFFFFFFFULL);  // > any real key

    const float4* sp = &spos[s];            // lane slice pointer, stride 8
    float4 buf[8];                          // software-pipelined chunk loads
#pragma unroll
    for (int u = 0; u < 8; ++u) buf[u] = sp[8 * u];

    int jlow = s;                           // local j of buf[0]
    for (int c = 0; c < 16; ++c) {          // 16 chunks x 8 candidates = 128
        double nk[8];
#pragma unroll
        for (int u = 0; u < 8; ++u) {
            // bit-exact numpy chain: no fma, (dx2+dy2)+dz2
            const float dx = __fsub_rn(pix, buf[u].x);
            const float dy = __fsub_rn(piy, buf[u].y);
            const float dz = __fsub_rn(piz, buf[u].z);
            const float d2 = __fadd_rn(
                __fadd_rn(__fmul_rn(dx, dx), __fmul_rn(dy, dy)),
                __fmul_rn(dz, dz));
            nk[u] = pack_key(d2, jlow + 8 * u);
        }
        if (c < 15) {                       // prefetch next chunk during sort
            sp += 64;
#pragma unroll
            for (int u = 0; u < 8; ++u) buf[u] = sp[8 * u];
        }
        jlow += 64;

        sort8(nk);
        // keep-16-smallest: INF-padded bitonic half-merge, then clean
#pragma unroll
        for (int t = 0; t < 8; ++t)
            key[8 + t] = fmin(key[8 + t], nk[7 - t]);
        clean16(key);
    }

    // butterfly merge of the 8 slice lists; afterwards ALL 8 lanes of a
    // group hold the identical ascending top-16 of the query.
#pragma unroll
    for (int r = 1; r <= 4; r <<= 1) {
        double nk[16];
#pragma unroll
        for (int t = 0; t < 16; ++t)
            nk[t] = __shfl_xor(key[15 - t], r, 64);  // reversed partner list
#pragma unroll
        for (int t = 0; t < 16; ++t)
            key[t] = fmin(key[t], nk[t]);            // stride-16 half-cleaner
        clean16(key);
    }

    // ---- fused epilogue: each group of 8 lanes emits its query's 16 rows ----
    const float4* x4 = (const float4*)x;
    const float4* W4 = (const float4*)Wm;   // W[10][32]: row = 8 float4
    float4 wcol[10];
#pragma unroll
    for (int m = 0; m < 10; ++m) wcol[m] = W4[m * 8 + s];
    const float4 bb = ((const float4*)bv)[s];

    float4* orow = (float4*)out + (size_t)(base + qi) * (K_ * 16);
#pragma unroll
    for (int k = 0; k < 16; ++k) {
        const int jl = (int)(u32)__double_as_longlong(key[k]);   // local j
        // channels 4s..4s+3 of x_j (lane-coalesced 128B per group)
        const float4 xj = x4[(size_t)(base + jl) * 8 + s];
        // enc channels 32+4s..32+4s+3
        const float4 pj = spos[jl];                              // broadcast
        const float rx = pix - pj.x, ry = piy - pj.y, rz = piz - pj.z;
        const float dist = sqrtf(rx * rx + ry * ry + rz * rz + 1e-12f);
        const float f[10] = {pix, piy, piz, pj.x, pj.y, pj.z, rx, ry, rz, dist};
        float4 acc = bb;
#pragma unroll
        for (int m = 0; m < 10; ++m) {
            acc.x = fmaf(f[m], wcol[m].x, acc.x);
            acc.y = fmaf(f[m], wcol[m].y, acc.y);
            acc.z = fmaf(f[m], wcol[m].z, acc.z);
            acc.w = fmaf(f[m], wcol[m].w, acc.w);
        }
        acc.x = fmaxf(acc.x, 0.0f);
        acc.y = fmaxf(acc.y, 0.0f);
        acc.z = fmaxf(acc.z, 0.0f);
        acc.w = fmaxf(acc.w, 0.0f);
        orow[k * 16 + s]     = xj;
        orow[k * 16 + 8 + s] = acc;
    }
}

extern "C" void kernel_launch(void* const* d_in, const int* in_sizes, int n_in,
                              void* d_out, int out_size, void* d_ws, size_t ws_size,
                              hipStream_t stream) {
    const float* x   = (const float*)d_in[0];
    const float* pos = (const float*)d_in[1];
    // d_in[2] = batch (unused: equal-size contiguous clouds)
    const float* Wm  = (const float*)d_in[3];
    const float* bv  = (const float*)d_in[4];
    float* out = (float*)d_out;

    knn_fused<<<B_ * 32, NTK, 0, stream>>>(pos, x, Wm, bv, out);
}